// Round 6
// baseline (112.253 us; speedup 1.0000x reference)
//
#include <hip/hip_runtime.h>

#define LD 68  // LDS row stride in floats: 272B = 17x16B, 16B-aligned rows

__global__ __launch_bounds__(256) void lagat_kernel(
    const float* __restrict__ adj,
    const float* __restrict__ feat_node,
    const int* __restrict__ idx,
    const int* __restrict__ head_ids,
    const int* __restrict__ tail_ids,
    const float* __restrict__ transform,
    const float* __restrict__ embed,
    const float* __restrict__ w1, const float* __restrict__ b1,
    const float* __restrict__ w2, const float* __restrict__ b2,
    const float* __restrict__ gamma1, const float* __restrict__ beta1,
    const float* __restrict__ gamma2, const float* __restrict__ beta2,
    float* __restrict__ out)
{
  __shared__ __align__(16) float Ab[64][LD];     // adjacency (0/1)
  __shared__ __align__(16) float featb[64][LD];  // transformed features
  __shared__ __align__(16) float Sb[64][LD];     // this chain's running state
  __shared__ __align__(16) float Xb[64][LD];     // init_feat, then X scratch
  __shared__ __align__(16) float Wb[4096];       // this chain's W
  __shared__ float prm[3][64];                   // gamma, beta, bias
  __shared__ float reach[3][64];                 // BFS reach (0/1)
  __shared__ float degs[64];
  __shared__ float corr[64];

  const int bid = blockIdx.x;
  const int g = bid >> 1, ch = bid & 1;          // graph, chain
  const int tid = threadIdx.x, nb = g * 64;

  // ---- phase 0: global -> LDS ----
  {
    const int r = tid >> 2, c0 = (tid & 3) * 16;
    const float4* asrc = (const float4*)&adj[(size_t)(nb + r) * 4096 + nb + c0];
#pragma unroll
    for (int u = 0; u < 4; ++u) *(float4*)&Ab[r][c0 + 4 * u] = asrc[u];
    if (c0 < 32) {
      const float4* fs = (const float4*)&feat_node[(size_t)(nb + r) * 32 + c0];
#pragma unroll
      for (int u = 0; u < 4; ++u) *(float4*)&Xb[r][c0 + 4 * u] = fs[u];
    } else {
      const float4* es =
          (const float4*)&embed[(size_t)idx[nb + r] * 32 + (c0 - 32)];
#pragma unroll
      for (int u = 0; u < 4; ++u) *(float4*)&Xb[r][c0 + 4 * u] = es[u];
    }
  }
  {
    const float* Wsrc = ch ? w2 : w1;
    const int base = tid * 16;  // 256*16 = 4096
#pragma unroll
    for (int u = 0; u < 4; ++u)
      *(float4*)&Wb[base + 4 * u] = *(const float4*)&Wsrc[base + 4 * u];
  }
  if (tid < 192) {
    const int a = tid >> 6, h = tid & 63;
    const float* s3 = ch ? ((a == 0) ? gamma2 : (a == 1) ? beta2 : b2)
                         : ((a == 0) ? gamma1 : (a == 1) ? beta1 : b1);
    prm[a][h] = s3[h];
  }
  __syncthreads();

  const int hl = head_ids[g] - nb, tl = tail_ids[g] - nb;
  const int root = ch ? tl : hl;   // BFS root for this chain's masks
  const int qrow = ch ? hl : tl;   // query feat row (opposite center)

  // ---- phase 1: reach0/1 + degs (waves 0-1) || transform GEMM (all) ----
  if (tid < 64) {
    reach[0][tid] = (tid == root) ? 1.f : 0.f;
    reach[1][tid] = (tid == root || Ab[root][tid] != 0.f) ? 1.f : 0.f;
  } else if (tid < 128) {
    const int i = tid & 63;
    float s = 0.f;
    for (int k = 0; k < 64; ++k) s += Ab[i][k];
    degs[i] = s;
  }
  {
    const int r = tid >> 2, c0 = (tid & 3) * 16;
    float acc[16] = {};
    for (int k = 0; k < 64; ++k) {
      const float a = Xb[r][k];
#pragma unroll
      for (int u = 0; u < 4; ++u) {
        const float4 t = *(const float4*)&transform[(size_t)k * 64 + c0 + 4 * u];
        acc[4*u]   = fmaf(a, t.x, acc[4*u]);
        acc[4*u+1] = fmaf(a, t.y, acc[4*u+1]);
        acc[4*u+2] = fmaf(a, t.z, acc[4*u+2]);
        acc[4*u+3] = fmaf(a, t.w, acc[4*u+3]);
      }
    }
#pragma unroll
    for (int u = 0; u < 4; ++u)
      *(float4*)&featb[r][c0 + 4 * u] =
          make_float4(acc[4*u], acc[4*u+1], acc[4*u+2], acc[4*u+3]);
  }
  __syncthreads();

  // ---- phase 2: reach2 + S init + (chain 0) layer-0 write ----
  if (tid < 64) {
    float v = (tid == root) ? 1.f : 0.f;
    for (int k = 0; k < 64; ++k)
      if (reach[1][k] != 0.f && Ab[k][tid] != 0.f) v = 1.f;
    reach[2][tid] = v;
  }
  {
    const int r = tid >> 2, c0 = (tid & 3) * 16;
#pragma unroll
    for (int u = 0; u < 4; ++u) {
      const float4 v = *(const float4*)&featb[r][c0 + 4 * u];
      *(float4*)&Sb[r][c0 + 4 * u] = v;
      if (ch == 0)
        *(float4*)&out[(size_t)(nb + r) * 256 + c0 + 4 * u] = v;
    }
  }
  __syncthreads();

  const int i4 = tid >> 2, q4 = tid & 3, c0 = q4 * 16;

  for (int hop = 2; hop >= 0; --hop) {
    // A: corr[i] = |dot(feat[qrow], S[i])|
    {
      float s = 0.f;
#pragma unroll
      for (int u = 0; u < 4; ++u) {
        const float4 qv = *(const float4*)&featb[qrow][c0 + 4 * u];
        const float4 sv = *(const float4*)&Sb[i4][c0 + 4 * u];
        s = fmaf(qv.x, sv.x, s); s = fmaf(qv.y, sv.y, s);
        s = fmaf(qv.z, sv.z, s); s = fmaf(qv.w, sv.w, s);
      }
      s += __shfl_xor(s, 1);
      s += __shfl_xor(s, 2);
      if (q4 == 0) corr[i4] = fabsf(s);
    }
    __syncthreads();

    // B+C+D fused: masked agg -> leaky/deg -> LN (in-register) -> +f*feat
    {
      float acc[16] = {};
      for (int j = 0; j < 64; ++j) {
        const float w = Ab[i4][j] * corr[j];  // branch-free 0/1 mask
        const float4 s0 = *(const float4*)&Sb[j][c0];
        const float4 s1 = *(const float4*)&Sb[j][c0 + 4];
        const float4 s2 = *(const float4*)&Sb[j][c0 + 8];
        const float4 s3 = *(const float4*)&Sb[j][c0 + 12];
        acc[0]  = fmaf(w, s0.x, acc[0]);  acc[1]  = fmaf(w, s0.y, acc[1]);
        acc[2]  = fmaf(w, s0.z, acc[2]);  acc[3]  = fmaf(w, s0.w, acc[3]);
        acc[4]  = fmaf(w, s1.x, acc[4]);  acc[5]  = fmaf(w, s1.y, acc[5]);
        acc[6]  = fmaf(w, s1.z, acc[6]);  acc[7]  = fmaf(w, s1.w, acc[7]);
        acc[8]  = fmaf(w, s2.x, acc[8]);  acc[9]  = fmaf(w, s2.y, acc[9]);
        acc[10] = fmaf(w, s2.z, acc[10]); acc[11] = fmaf(w, s2.w, acc[11]);
        acc[12] = fmaf(w, s3.x, acc[12]); acc[13] = fmaf(w, s3.y, acc[13]);
        acc[14] = fmaf(w, s3.z, acc[14]); acc[15] = fmaf(w, s3.w, acc[15]);
      }
      const float dn = 1.f / (degs[i4] + 1e-8f);
      float x[16], sm = 0.f, s2m = 0.f;
#pragma unroll
      for (int c = 0; c < 16; ++c) {
        float z = acc[c];
        z = (z > 0.f) ? z : 0.01f * z;    // leaky_relu slope 0.01
        z *= dn;
        x[c] = z; sm += z; s2m = fmaf(z, z, s2m);
      }
      sm  += __shfl_xor(sm, 1);  sm  += __shfl_xor(sm, 2);
      s2m += __shfl_xor(s2m, 1); s2m += __shfl_xor(s2m, 2);
      const float mu = sm * 0.015625f;
      const float var = fmaxf(s2m * 0.015625f - mu * mu, 0.f);
      const float rstd = rsqrtf(var + 1e-5f);
      const float f = reach[hop][i4];
#pragma unroll
      for (int c = 0; c < 16; ++c) {
        const int cc = c0 + c;
        x[c] = fmaf(f, featb[i4][cc],
                    prm[0][cc] * (x[c] - mu) * rstd + prm[1][cc]);
      }
#pragma unroll
      for (int u = 0; u < 4; ++u)
        *(float4*)&Xb[i4][c0 + 4 * u] =
            make_float4(x[4*u], x[4*u+1], x[4*u+2], x[4*u+3]);
    }
    __syncthreads();

    // E: S[i] = f ? relu(X[i] @ W + b) : S[i]
    {
      float acc[16];
#pragma unroll
      for (int c = 0; c < 16; ++c) acc[c] = prm[2][c0 + c];
      for (int k = 0; k < 64; ++k) {
        const float xv = Xb[i4][k];
        const float4 w0 = *(const float4*)&Wb[k * 64 + c0];
        const float4 w1v = *(const float4*)&Wb[k * 64 + c0 + 4];
        const float4 w2v = *(const float4*)&Wb[k * 64 + c0 + 8];
        const float4 w3v = *(const float4*)&Wb[k * 64 + c0 + 12];
        acc[0]  = fmaf(xv, w0.x,  acc[0]);  acc[1]  = fmaf(xv, w0.y,  acc[1]);
        acc[2]  = fmaf(xv, w0.z,  acc[2]);  acc[3]  = fmaf(xv, w0.w,  acc[3]);
        acc[4]  = fmaf(xv, w1v.x, acc[4]);  acc[5]  = fmaf(xv, w1v.y, acc[5]);
        acc[6]  = fmaf(xv, w1v.z, acc[6]);  acc[7]  = fmaf(xv, w1v.w, acc[7]);
        acc[8]  = fmaf(xv, w2v.x, acc[8]);  acc[9]  = fmaf(xv, w2v.y, acc[9]);
        acc[10] = fmaf(xv, w2v.z, acc[10]); acc[11] = fmaf(xv, w2v.w, acc[11]);
        acc[12] = fmaf(xv, w3v.x, acc[12]); acc[13] = fmaf(xv, w3v.y, acc[13]);
        acc[14] = fmaf(xv, w3v.z, acc[14]); acc[15] = fmaf(xv, w3v.w, acc[15]);
      }
      if (reach[hop][i4] != 0.f) {
#pragma unroll
        for (int u = 0; u < 4; ++u)
          *(float4*)&Sb[i4][c0 + 4 * u] = make_float4(
              fmaxf(acc[4*u], 0.f),   fmaxf(acc[4*u+1], 0.f),
              fmaxf(acc[4*u+2], 0.f), fmaxf(acc[4*u+3], 0.f));
      }
    }
    __syncthreads();

    // layer write L = 3-hop: out += S (other chain's block adds the rest)
    {
      const int L = 3 - hop;
      float* dst = &out[(size_t)(nb + i4) * 256 + (size_t)L * 64 + c0];
#pragma unroll
      for (int c = 0; c < 16; ++c) atomicAdd(&dst[c], Sb[i4][c0 + c]);
    }
    // no barrier needed: atomics only read Sb; next phase A also only
    // reads Sb/featb and its corr write is consumed after the next barrier
  }
}

extern "C" void kernel_launch(void* const* d_in, const int* in_sizes, int n_in,
                              void* d_out, int out_size, void* d_ws, size_t ws_size,
                              hipStream_t stream) {
  const float* adj       = (const float*)d_in[0];
  const float* feat_node = (const float*)d_in[1];
  const int*   idx       = (const int*)d_in[2];
  const int*   head_ids  = (const int*)d_in[3];
  const int*   tail_ids  = (const int*)d_in[4];
  // d_in[5] = graph_indices (implied by block structure, unused)
  const float* transform = (const float*)d_in[6];
  const float* embed     = (const float*)d_in[7];
  const float* w1v    = (const float*)d_in[8];
  const float* b1v    = (const float*)d_in[9];
  const float* w2v    = (const float*)d_in[10];
  const float* b2v    = (const float*)d_in[11];
  const float* gamma1 = (const float*)d_in[12];
  const float* beta1  = (const float*)d_in[13];
  const float* gamma2 = (const float*)d_in[14];
  const float* beta2  = (const float*)d_in[15];

  hipMemsetAsync(d_out, 0, (size_t)out_size * sizeof(float), stream);
  lagat_kernel<<<128, 256, 0, stream>>>(adj, feat_node, idx, head_ids, tail_ids,
      transform, embed, w1v, b1v, w2v, b2v, gamma1, beta1, gamma2, beta2,
      (float*)d_out);
}

// Round 7
// 42.497 us; speedup vs baseline: 2.6415x; 2.6415x over previous
//
#include <hip/hip_runtime.h>

#define LD 68  // LDS row stride in floats: 272B = 17x16B, 16B-aligned rows

__global__ __launch_bounds__(512) void lagat_kernel(
    const float* __restrict__ adj,
    const float* __restrict__ feat_node,
    const int* __restrict__ idx,
    const int* __restrict__ head_ids,
    const int* __restrict__ tail_ids,
    const float* __restrict__ transform,
    const float* __restrict__ embed,
    const float* __restrict__ w1, const float* __restrict__ b1,
    const float* __restrict__ w2, const float* __restrict__ b2,
    const float* __restrict__ gamma1, const float* __restrict__ beta1,
    const float* __restrict__ gamma2, const float* __restrict__ beta2,
    float* __restrict__ out)
{
  __shared__ __align__(16) float Ab[64][LD];     // adjacency (0/1, symmetric)
  __shared__ __align__(16) float featb[64][LD];  // transformed features
  __shared__ __align__(16) float Sb[2][64][LD];  // head/tail running state
  __shared__ __align__(16) float Xb[2][64][LD];  // init_feat, then X scratch
  __shared__ __align__(16) float Wb[2][4096];    // w1, w2 staged
  __shared__ float prm[2][3][64];                // gamma, beta, bias per chain
  __shared__ float reach[2][3][64];              // BFS reach (0/1)
  __shared__ float degs[64];
  __shared__ float corr[2][64];

  const int g = blockIdx.x, tid = threadIdx.x, nb = g * 64;

  // ---- P0: global -> LDS ----
  {
    const int r = tid >> 3, c8 = (tid & 7) * 8;
    const float4* asrc = (const float4*)&adj[(size_t)(nb + r) * 4096 + nb + c8];
    *(float4*)&Ab[r][c8]     = asrc[0];
    *(float4*)&Ab[r][c8 + 4] = asrc[1];
    if (c8 < 32) {
      const float4* fs = (const float4*)&feat_node[(size_t)(nb + r) * 32 + c8];
      *(float4*)&Xb[0][r][c8]     = fs[0];
      *(float4*)&Xb[0][r][c8 + 4] = fs[1];
    } else {
      const float4* es = (const float4*)&embed[(size_t)idx[nb + r] * 32 + (c8 - 32)];
      *(float4*)&Xb[0][r][c8]     = es[0];
      *(float4*)&Xb[0][r][c8 + 4] = es[1];
    }
  }
  {
    const int base = tid * 16;  // 512*16 = 8192 = 2*4096
    const float* src = (base < 4096) ? &w1[base] : &w2[base - 4096];
    float* dst = &Wb[0][0] + base;
#pragma unroll
    for (int u = 0; u < 4; ++u)
      *(float4*)&dst[u * 4] = *(const float4*)&src[u * 4];
  }
  if (tid < 384) {
    const int a = tid >> 6, h = tid & 63;
    const float* s6 = (a == 0) ? gamma1 : (a == 1) ? beta1 : (a == 2) ? b1
                    : (a == 3) ? gamma2 : (a == 4) ? beta2 : b2;
    prm[a / 3][a % 3][h] = s6[h];
  }
  __syncthreads();

  const int hl = head_ids[g] - nb, tl = tail_ids[g] - nb;

  // ---- P1: reach0/1 + degs (subset) || transform GEMM 2x4-tiled (all) ----
  if (tid < 128) {
    const int c = tid >> 6, j = tid & 63;
    const int root = c ? tl : hl;
    reach[c][0][j] = (j == root) ? 1.f : 0.f;
    reach[c][1][j] = (j == root || Ab[root][j] != 0.f) ? 1.f : 0.f;
  } else if (tid < 192) {
    const int i = tid & 63;
    float s = 0.f;
    for (int k = 0; k < 64; ++k) s += Ab[i][k];
    degs[i] = s;
  }
  {
    const int c0g = (tid & 15) * 4, r0g = (tid >> 4) * 2;
    float a0c[4] = {}, a1c[4] = {};
    for (int k = 0; k < 64; ++k) {
      const float4 t4 = *(const float4*)&transform[(size_t)k * 64 + c0g];
      const float a0 = Xb[0][r0g][k], a1 = Xb[0][r0g + 1][k];
      a0c[0] = fmaf(a0, t4.x, a0c[0]); a0c[1] = fmaf(a0, t4.y, a0c[1]);
      a0c[2] = fmaf(a0, t4.z, a0c[2]); a0c[3] = fmaf(a0, t4.w, a0c[3]);
      a1c[0] = fmaf(a1, t4.x, a1c[0]); a1c[1] = fmaf(a1, t4.y, a1c[1]);
      a1c[2] = fmaf(a1, t4.z, a1c[2]); a1c[3] = fmaf(a1, t4.w, a1c[3]);
    }
    *(float4*)&featb[r0g][c0g]     = make_float4(a0c[0], a0c[1], a0c[2], a0c[3]);
    *(float4*)&featb[r0g + 1][c0g] = make_float4(a1c[0], a1c[1], a1c[2], a1c[3]);
  }
  __syncthreads();

  // ---- P2: reach2 (subset) + S init + layer-0 write (all) ----
  if (tid < 128) {
    const int c = tid >> 6, j = tid & 63;
    const int root = c ? tl : hl;
    float v = (j == root) ? 1.f : 0.f;
    for (int k = 0; k < 64; ++k)
      if (reach[c][1][k] != 0.f && Ab[k][j] != 0.f) v = 1.f;
    reach[c][2][j] = v;
  }
  {
    const int r = tid >> 3, c8 = (tid & 7) * 8;
#pragma unroll
    for (int u = 0; u < 2; ++u) {
      const float4 v = *(const float4*)&featb[r][c8 + 4 * u];
      *(float4*)&Sb[0][r][c8 + 4 * u] = v;
      *(float4*)&Sb[1][r][c8 + 4 * u] = v;
      *(float4*)&out[(size_t)(nb + r) * 256 + c8 + 4 * u] = v;
    }
  }
  __syncthreads();

  // ---- hop-loop mappings + register preloads (loop-invariant) ----
  const int ch = tid >> 8, t = tid & 255;
  const int c0 = (t & 15) * 4, r0 = (t >> 4) * 4;  // 4x4 tile (B/D/E)
  const int iA = t >> 2, qA = t & 3;               // A-phase map
  const int qrow = ch ? hl : tl;                   // opposite-center query
  const int r8 = tid >> 3, cc8 = (tid & 7) * 8;    // layer-write map

  float dn[4], ga[4], be[4], bb[4];
  float4 ft[4], qv[4];
#pragma unroll
  for (int m = 0; m < 4; ++m) {
    dn[m] = 1.f / (degs[r0 + m] + 1e-8f);
    ft[m] = *(const float4*)&featb[r0 + m][c0];
  }
#pragma unroll
  for (int c = 0; c < 4; ++c) {
    ga[c] = prm[ch][0][c0 + c];
    be[c] = prm[ch][1][c0 + c];
    bb[c] = prm[ch][2][c0 + c];
  }
#pragma unroll
  for (int u = 0; u < 4; ++u)
    qv[u] = *(const float4*)&featb[qrow][qA * 16 + 4 * u];

  for (int hop = 2; hop >= 0; --hop) {
    // deferred layer write (L = 2-hop) + A: corr[i] = |dot(q, S[i])|
    if (hop != 2) {
      const int L = 2 - hop;
#pragma unroll
      for (int u = 0; u < 2; ++u) {
        const float4 a = *(const float4*)&Sb[0][r8][cc8 + 4 * u];
        const float4 b = *(const float4*)&Sb[1][r8][cc8 + 4 * u];
        *(float4*)&out[(size_t)(nb + r8) * 256 + (size_t)L * 64 + cc8 + 4 * u] =
            make_float4(a.x + b.x, a.y + b.y, a.z + b.z, a.w + b.w);
      }
    }
    {
      float s = 0.f;
#pragma unroll
      for (int u = 0; u < 4; ++u) {
        const float4 sv = *(const float4*)&Sb[ch][iA][qA * 16 + 4 * u];
        s = fmaf(qv[u].x, sv.x, s); s = fmaf(qv[u].y, sv.y, s);
        s = fmaf(qv[u].z, sv.z, s); s = fmaf(qv[u].w, sv.w, s);
      }
      s += __shfl_xor(s, 1);
      s += __shfl_xor(s, 2);
      if (qA == 0) corr[ch][iA] = fabsf(s);
    }
    __syncthreads();

    // B+C+D fused, 4x4 register tile.  Ab symmetric => Ab[j][r] == Ab[r][j].
    {
      float acc[4][4] = {};
      for (int j = 0; j < 64; ++j) {
        const float cj = corr[ch][j];
        const float4 a4 = *(const float4*)&Ab[j][r0];      // w for 4 rows
        const float4 s4 = *(const float4*)&Sb[ch][j][c0];  // S cols
        const float w0 = a4.x * cj, w1_ = a4.y * cj;
        const float w2_ = a4.z * cj, w3_ = a4.w * cj;
        acc[0][0] = fmaf(w0, s4.x, acc[0][0]); acc[0][1] = fmaf(w0, s4.y, acc[0][1]);
        acc[0][2] = fmaf(w0, s4.z, acc[0][2]); acc[0][3] = fmaf(w0, s4.w, acc[0][3]);
        acc[1][0] = fmaf(w1_, s4.x, acc[1][0]); acc[1][1] = fmaf(w1_, s4.y, acc[1][1]);
        acc[1][2] = fmaf(w1_, s4.z, acc[1][2]); acc[1][3] = fmaf(w1_, s4.w, acc[1][3]);
        acc[2][0] = fmaf(w2_, s4.x, acc[2][0]); acc[2][1] = fmaf(w2_, s4.y, acc[2][1]);
        acc[2][2] = fmaf(w2_, s4.z, acc[2][2]); acc[2][3] = fmaf(w2_, s4.w, acc[2][3]);
        acc[3][0] = fmaf(w3_, s4.x, acc[3][0]); acc[3][1] = fmaf(w3_, s4.y, acc[3][1]);
        acc[3][2] = fmaf(w3_, s4.z, acc[3][2]); acc[3][3] = fmaf(w3_, s4.w, acc[3][3]);
      }
      float x[4][4], sm[4], s2[4];
#pragma unroll
      for (int m = 0; m < 4; ++m) {
        float smm = 0.f, s2m = 0.f;
#pragma unroll
        for (int c = 0; c < 4; ++c) {
          float z = acc[m][c];
          z = (z > 0.f) ? z : 0.01f * z;   // leaky_relu slope 0.01
          z *= dn[m];
          x[m][c] = z; smm += z; s2m = fmaf(z, z, s2m);
        }
        sm[m] = smm; s2[m] = s2m;
      }
#pragma unroll
      for (int mask = 1; mask < 16; mask <<= 1) {  // reduce 16 lanes (same rows)
#pragma unroll
        for (int m = 0; m < 4; ++m) {
          sm[m] += __shfl_xor(sm[m], mask);
          s2[m] += __shfl_xor(s2[m], mask);
        }
      }
#pragma unroll
      for (int m = 0; m < 4; ++m) {
        const float mu = sm[m] * 0.015625f;
        const float var = fmaxf(s2[m] * 0.015625f - mu * mu, 0.f);
        const float rstd = rsqrtf(var + 1e-5f);
        const float f = reach[ch][hop][r0 + m];
        float4 xv;
        xv.x = fmaf(f, ft[m].x, ga[0] * (x[m][0] - mu) * rstd + be[0]);
        xv.y = fmaf(f, ft[m].y, ga[1] * (x[m][1] - mu) * rstd + be[1]);
        xv.z = fmaf(f, ft[m].z, ga[2] * (x[m][2] - mu) * rstd + be[2]);
        xv.w = fmaf(f, ft[m].w, ga[3] * (x[m][3] - mu) * rstd + be[3]);
        *(float4*)&Xb[ch][r0 + m][c0] = xv;
      }
    }
    __syncthreads();

    // E: S[i] = f ? relu(X[i] @ W + b) : S[i], 4x4 register tile
    {
      float acc[4][4];
#pragma unroll
      for (int m = 0; m < 4; ++m)
#pragma unroll
        for (int c = 0; c < 4; ++c) acc[m][c] = bb[c];
      for (int k0 = 0; k0 < 64; k0 += 4) {
        float4 xr[4], wv[4];
#pragma unroll
        for (int m = 0; m < 4; ++m)
          xr[m] = *(const float4*)&Xb[ch][r0 + m][k0];
#pragma unroll
        for (int kk = 0; kk < 4; ++kk)
          wv[kk] = *(const float4*)&Wb[ch][(k0 + kk) * 64 + c0];
#pragma unroll
        for (int m = 0; m < 4; ++m) {
          acc[m][0] = fmaf(xr[m].x, wv[0].x, acc[m][0]);
          acc[m][1] = fmaf(xr[m].x, wv[0].y, acc[m][1]);
          acc[m][2] = fmaf(xr[m].x, wv[0].z, acc[m][2]);
          acc[m][3] = fmaf(xr[m].x, wv[0].w, acc[m][3]);
          acc[m][0] = fmaf(xr[m].y, wv[1].x, acc[m][0]);
          acc[m][1] = fmaf(xr[m].y, wv[1].y, acc[m][1]);
          acc[m][2] = fmaf(xr[m].y, wv[1].z, acc[m][2]);
          acc[m][3] = fmaf(xr[m].y, wv[1].w, acc[m][3]);
          acc[m][0] = fmaf(xr[m].z, wv[2].x, acc[m][0]);
          acc[m][1] = fmaf(xr[m].z, wv[2].y, acc[m][1]);
          acc[m][2] = fmaf(xr[m].z, wv[2].z, acc[m][2]);
          acc[m][3] = fmaf(xr[m].z, wv[2].w, acc[m][3]);
          acc[m][0] = fmaf(xr[m].w, wv[3].x, acc[m][0]);
          acc[m][1] = fmaf(xr[m].w, wv[3].y, acc[m][1]);
          acc[m][2] = fmaf(xr[m].w, wv[3].z, acc[m][2]);
          acc[m][3] = fmaf(xr[m].w, wv[3].w, acc[m][3]);
        }
      }
#pragma unroll
      for (int m = 0; m < 4; ++m) {
        if (reach[ch][hop][r0 + m] != 0.f) {
          *(float4*)&Sb[ch][r0 + m][c0] = make_float4(
              fmaxf(acc[m][0], 0.f), fmaxf(acc[m][1], 0.f),
              fmaxf(acc[m][2], 0.f), fmaxf(acc[m][3], 0.f));
        }
      }
    }
    __syncthreads();
  }

  // final layer 3 write
  {
#pragma unroll
    for (int u = 0; u < 2; ++u) {
      const float4 a = *(const float4*)&Sb[0][r8][cc8 + 4 * u];
      const float4 b = *(const float4*)&Sb[1][r8][cc8 + 4 * u];
      *(float4*)&out[(size_t)(nb + r8) * 256 + 192 + cc8 + 4 * u] =
          make_float4(a.x + b.x, a.y + b.y, a.z + b.z, a.w + b.w);
    }
  }
}

extern "C" void kernel_launch(void* const* d_in, const int* in_sizes, int n_in,
                              void* d_out, int out_size, void* d_ws, size_t ws_size,
                              hipStream_t stream) {
  const float* adj       = (const float*)d_in[0];
  const float* feat_node = (const float*)d_in[1];
  const int*   idx       = (const int*)d_in[2];
  const int*   head_ids  = (const int*)d_in[3];
  const int*   tail_ids  = (const int*)d_in[4];
  // d_in[5] = graph_indices (implied by block structure, unused)
  const float* transform = (const float*)d_in[6];
  const float* embed     = (const float*)d_in[7];
  const float* w1v    = (const float*)d_in[8];
  const float* b1v    = (const float*)d_in[9];
  const float* w2v    = (const float*)d_in[10];
  const float* b2v    = (const float*)d_in[11];
  const float* gamma1 = (const float*)d_in[12];
  const float* beta1  = (const float*)d_in[13];
  const float* gamma2 = (const float*)d_in[14];
  const float* beta2  = (const float*)d_in[15];

  lagat_kernel<<<64, 512, 0, stream>>>(adj, feat_node, idx, head_ids, tail_ids,
      transform, embed, w1v, b1v, w2v, b2v, gamma1, beta1, gamma2, beta2,
      (float*)d_out);
}

// Round 8
// 36.832 us; speedup vs baseline: 3.0477x; 1.1538x over previous
//
#include <hip/hip_runtime.h>

#define LD 68  // fp32 LDS row stride: 272B = 17x16B
#define XP 72  // bf16 X row pitch: 144B = 9x16B, conflict-free frag reads

typedef float f32x4 __attribute__((ext_vector_type(4)));
typedef short s16x8 __attribute__((ext_vector_type(8)));

__device__ __forceinline__ unsigned short f2bf(float f) {
  union { float f; unsigned int u; } v; v.f = f;
  const unsigned int r = (v.u + 0x7fffu + ((v.u >> 16) & 1u)) >> 16;
  return (unsigned short)r;
}
__device__ __forceinline__ float bf2f(unsigned short h) {
  union { unsigned int u; float f; } v; v.u = ((unsigned int)h) << 16;
  return v.f;
}

__global__ __launch_bounds__(512) void lagat_kernel(
    const float* __restrict__ adj,
    const float* __restrict__ feat_node,
    const int* __restrict__ idx,
    const int* __restrict__ head_ids,
    const int* __restrict__ tail_ids,
    const float* __restrict__ transform,
    const float* __restrict__ embed,
    const float* __restrict__ w1, const float* __restrict__ b1,
    const float* __restrict__ w2, const float* __restrict__ b2,
    const float* __restrict__ gamma1, const float* __restrict__ beta1,
    const float* __restrict__ gamma2, const float* __restrict__ beta2,
    float* __restrict__ out)
{
  __shared__ __align__(16) float Ab[64][LD];     // adjacency (0/1, symmetric)
  __shared__ __align__(16) float featb[64][LD];  // transformed features
  __shared__ __align__(16) float Sb[2][64][LD];  // head/tail running state
  __shared__ __align__(16) float Ib[64][LD];     // init_feat scratch
  __shared__ __align__(16) unsigned short Xh[2][64][XP];  // X hi (bf16)
  __shared__ __align__(16) unsigned short Xl[2][64][XP];  // X lo (bf16)
  __shared__ float prm[2][3][64];                // gamma, beta, bias per chain
  __shared__ float reach[2][3][64];              // BFS reach (0/1)
  __shared__ float degs[64];
  __shared__ float corr[2][64];

  const int g = blockIdx.x, tid = threadIdx.x, nb = g * 64;

  // ---- P0: global -> LDS ----
  {
    const int r = tid >> 3, c8 = (tid & 7) * 8;
    const float4* asrc = (const float4*)&adj[(size_t)(nb + r) * 4096 + nb + c8];
    *(float4*)&Ab[r][c8]     = asrc[0];
    *(float4*)&Ab[r][c8 + 4] = asrc[1];
    if (c8 < 32) {
      const float4* fs = (const float4*)&feat_node[(size_t)(nb + r) * 32 + c8];
      *(float4*)&Ib[r][c8]     = fs[0];
      *(float4*)&Ib[r][c8 + 4] = fs[1];
    } else {
      const float4* es = (const float4*)&embed[(size_t)idx[nb + r] * 32 + (c8 - 32)];
      *(float4*)&Ib[r][c8]     = es[0];
      *(float4*)&Ib[r][c8 + 4] = es[1];
    }
  }
  if (tid < 384) {
    const int a = tid >> 6, h = tid & 63;
    const float* s6 = (a == 0) ? gamma1 : (a == 1) ? beta1 : (a == 2) ? b1
                    : (a == 3) ? gamma2 : (a == 4) ? beta2 : b2;
    prm[a / 3][a % 3][h] = s6[h];
  }
  __syncthreads();

  const int hl = head_ids[g] - nb, tl = tail_ids[g] - nb;

  // ---- E-phase wave mapping + W fragments from global (once) ----
  const int wv = tid >> 6, lane = tid & 63;
  const int ech = wv >> 2, eslab = (wv & 3) * 16;
  const int ln15 = lane & 15, lg = lane >> 4;
  s16x8 wfh[8], wfl[8];   // [ct*2+ks], hi/lo bf16 B-frags, persist in VGPRs
  float ebias[4];
  {
    const float* Wg = ech ? w2 : w1;
#pragma unroll
    for (int ct = 0; ct < 4; ++ct) {
#pragma unroll
      for (int ks = 0; ks < 2; ++ks) {
        s16x8 h, lo;
#pragma unroll
        for (int j = 0; j < 8; ++j) {
          const float w = Wg[(size_t)(ks * 32 + lg * 8 + j) * 64 + ct * 16 + ln15];
          const unsigned short hu = f2bf(w);
          h[j] = (short)hu;
          lo[j] = (short)f2bf(w - bf2f(hu));
        }
        wfh[ct * 2 + ks] = h;
        wfl[ct * 2 + ks] = lo;
      }
    }
  }

  // ---- P1: reach0/1 + degs (subset) || transform GEMM 2x4-tiled (all) ----
  if (tid < 128) {
    const int c = tid >> 6, j = tid & 63;
    const int root = c ? tl : hl;
    reach[c][0][j] = (j == root) ? 1.f : 0.f;
    reach[c][1][j] = (j == root || Ab[root][j] != 0.f) ? 1.f : 0.f;
  } else if (tid < 192) {
    const int i = tid & 63;
    float s = 0.f;
    for (int k = 0; k < 64; ++k) s += Ab[i][k];
    degs[i] = s;
  }
  {
    const int c0g = (tid & 15) * 4, r0g = (tid >> 4) * 2;
    float a0c[4] = {}, a1c[4] = {};
    for (int k = 0; k < 64; ++k) {
      const float4 t4 = *(const float4*)&transform[(size_t)k * 64 + c0g];
      const float a0 = Ib[r0g][k], a1 = Ib[r0g + 1][k];
      a0c[0] = fmaf(a0, t4.x, a0c[0]); a0c[1] = fmaf(a0, t4.y, a0c[1]);
      a0c[2] = fmaf(a0, t4.z, a0c[2]); a0c[3] = fmaf(a0, t4.w, a0c[3]);
      a1c[0] = fmaf(a1, t4.x, a1c[0]); a1c[1] = fmaf(a1, t4.y, a1c[1]);
      a1c[2] = fmaf(a1, t4.z, a1c[2]); a1c[3] = fmaf(a1, t4.w, a1c[3]);
    }
    *(float4*)&featb[r0g][c0g]     = make_float4(a0c[0], a0c[1], a0c[2], a0c[3]);
    *(float4*)&featb[r0g + 1][c0g] = make_float4(a1c[0], a1c[1], a1c[2], a1c[3]);
  }
  __syncthreads();

  // ---- P2: reach2 (subset) + S init + layer-0 write (all) ----
  if (tid < 128) {
    const int c = tid >> 6, j = tid & 63;
    const int root = c ? tl : hl;
    float v = (j == root) ? 1.f : 0.f;
    for (int k = 0; k < 64; ++k)
      if (reach[c][1][k] != 0.f && Ab[k][j] != 0.f) v = 1.f;
    reach[c][2][j] = v;
  }
  {
    const int r = tid >> 3, c8 = (tid & 7) * 8;
#pragma unroll
    for (int u = 0; u < 2; ++u) {
      const float4 v = *(const float4*)&featb[r][c8 + 4 * u];
      *(float4*)&Sb[0][r][c8 + 4 * u] = v;
      *(float4*)&Sb[1][r][c8 + 4 * u] = v;
      *(float4*)&out[(size_t)(nb + r) * 256 + c8 + 4 * u] = v;
    }
  }
  // E bias per lane-col (prm ready since P0 barrier)
#pragma unroll
  for (int ct = 0; ct < 4; ++ct) ebias[ct] = prm[ech][2][ct * 16 + ln15];
  __syncthreads();

  // ---- hop-loop mappings + register preloads (loop-invariant) ----
  const int ch = tid >> 8, t = tid & 255;
  const int c0 = (t & 15) * 4, r0 = (t >> 4) * 4;  // 4x4 tile (B/D)
  const int iA = t >> 2, qA = t & 3;               // A-phase map
  const int qrow = ch ? hl : tl;                   // opposite-center query
  const int r8 = tid >> 3, cc8 = (tid & 7) * 8;    // layer-write map

  float dn[4], ga[4], be[4];
  float4 ft[4], qv[4];
#pragma unroll
  for (int m = 0; m < 4; ++m) {
    dn[m] = 1.f / (degs[r0 + m] + 1e-8f);
    ft[m] = *(const float4*)&featb[r0 + m][c0];
  }
#pragma unroll
  for (int c = 0; c < 4; ++c) {
    ga[c] = prm[ch][0][c0 + c];
    be[c] = prm[ch][1][c0 + c];
  }
#pragma unroll
  for (int u = 0; u < 4; ++u)
    qv[u] = *(const float4*)&featb[qrow][qA * 16 + 4 * u];

  for (int hop = 2; hop >= 0; --hop) {
    // deferred layer write (L = 2-hop) + A: corr[i] = |dot(q, S[i])|
    if (hop != 2) {
      const int L = 2 - hop;
#pragma unroll
      for (int u = 0; u < 2; ++u) {
        const float4 a = *(const float4*)&Sb[0][r8][cc8 + 4 * u];
        const float4 b = *(const float4*)&Sb[1][r8][cc8 + 4 * u];
        *(float4*)&out[(size_t)(nb + r8) * 256 + (size_t)L * 64 + cc8 + 4 * u] =
            make_float4(a.x + b.x, a.y + b.y, a.z + b.z, a.w + b.w);
      }
    }
    {
      float s = 0.f;
#pragma unroll
      for (int u = 0; u < 4; ++u) {
        const float4 sv = *(const float4*)&Sb[ch][iA][qA * 16 + 4 * u];
        s = fmaf(qv[u].x, sv.x, s); s = fmaf(qv[u].y, sv.y, s);
        s = fmaf(qv[u].z, sv.z, s); s = fmaf(qv[u].w, sv.w, s);
      }
      s += __shfl_xor(s, 1);
      s += __shfl_xor(s, 2);
      if (qA == 0) corr[ch][iA] = fabsf(s);
    }
    __syncthreads();

    // B+C+D fused, 4x4 register tile; D writes X as bf16 hi/lo
    {
      float acc[4][4] = {};
      for (int j = 0; j < 64; ++j) {
        const float cj = corr[ch][j];
        const float4 a4 = *(const float4*)&Ab[j][r0];      // symmetric adj
        const float4 s4 = *(const float4*)&Sb[ch][j][c0];
        const float w0 = a4.x * cj, w1_ = a4.y * cj;
        const float w2_ = a4.z * cj, w3_ = a4.w * cj;
        acc[0][0] = fmaf(w0, s4.x, acc[0][0]); acc[0][1] = fmaf(w0, s4.y, acc[0][1]);
        acc[0][2] = fmaf(w0, s4.z, acc[0][2]); acc[0][3] = fmaf(w0, s4.w, acc[0][3]);
        acc[1][0] = fmaf(w1_, s4.x, acc[1][0]); acc[1][1] = fmaf(w1_, s4.y, acc[1][1]);
        acc[1][2] = fmaf(w1_, s4.z, acc[1][2]); acc[1][3] = fmaf(w1_, s4.w, acc[1][3]);
        acc[2][0] = fmaf(w2_, s4.x, acc[2][0]); acc[2][1] = fmaf(w2_, s4.y, acc[2][1]);
        acc[2][2] = fmaf(w2_, s4.z, acc[2][2]); acc[2][3] = fmaf(w2_, s4.w, acc[2][3]);
        acc[3][0] = fmaf(w3_, s4.x, acc[3][0]); acc[3][1] = fmaf(w3_, s4.y, acc[3][1]);
        acc[3][2] = fmaf(w3_, s4.z, acc[3][2]); acc[3][3] = fmaf(w3_, s4.w, acc[3][3]);
      }
      float x[4][4], sm[4], s2[4];
#pragma unroll
      for (int m = 0; m < 4; ++m) {
        float smm = 0.f, s2m = 0.f;
#pragma unroll
        for (int c = 0; c < 4; ++c) {
          float z = acc[m][c];
          z = (z > 0.f) ? z : 0.01f * z;   // leaky_relu slope 0.01
          z *= dn[m];
          x[m][c] = z; smm += z; s2m = fmaf(z, z, s2m);
        }
        sm[m] = smm; s2[m] = s2m;
      }
#pragma unroll
      for (int mask = 1; mask < 16; mask <<= 1) {
#pragma unroll
        for (int m = 0; m < 4; ++m) {
          sm[m] += __shfl_xor(sm[m], mask);
          s2[m] += __shfl_xor(s2[m], mask);
        }
      }
#pragma unroll
      for (int m = 0; m < 4; ++m) {
        const float mu = sm[m] * 0.015625f;
        const float var = fmaxf(s2[m] * 0.015625f - mu * mu, 0.f);
        const float rstd = rsqrtf(var + 1e-5f);
        const float f = reach[ch][hop][r0 + m];
        float xv[4];
        xv[0] = fmaf(f, ft[m].x, ga[0] * (x[m][0] - mu) * rstd + be[0]);
        xv[1] = fmaf(f, ft[m].y, ga[1] * (x[m][1] - mu) * rstd + be[1]);
        xv[2] = fmaf(f, ft[m].z, ga[2] * (x[m][2] - mu) * rstd + be[2]);
        xv[3] = fmaf(f, ft[m].w, ga[3] * (x[m][3] - mu) * rstd + be[3]);
        ushort4 h4, l4;
        h4.x = f2bf(xv[0]); l4.x = f2bf(xv[0] - bf2f(h4.x));
        h4.y = f2bf(xv[1]); l4.y = f2bf(xv[1] - bf2f(h4.y));
        h4.z = f2bf(xv[2]); l4.z = f2bf(xv[2] - bf2f(h4.z));
        h4.w = f2bf(xv[3]); l4.w = f2bf(xv[3] - bf2f(h4.w));
        *(ushort4*)&Xh[ch][r0 + m][c0] = h4;
        *(ushort4*)&Xl[ch][r0 + m][c0] = l4;
      }
    }
    __syncthreads();

    // E (MFMA): S[i] = f ? relu(X[i] @ W + b) : S[i]
    {
      s16x8 xhf[2], xlf[2];
      const int xrow = eslab + ln15;
#pragma unroll
      for (int ks = 0; ks < 2; ++ks) {
        xhf[ks] = *(const s16x8*)&Xh[ech][xrow][lg * 8 + ks * 32];
        xlf[ks] = *(const s16x8*)&Xl[ech][xrow][lg * 8 + ks * 32];
      }
      f32x4 acc[4];
#pragma unroll
      for (int ct = 0; ct < 4; ++ct) {
        acc[ct] = (f32x4){ebias[ct], ebias[ct], ebias[ct], ebias[ct]};
#pragma unroll
        for (int ks = 0; ks < 2; ++ks) {
          acc[ct] = __builtin_amdgcn_mfma_f32_16x16x32_bf16(
              xhf[ks], wfh[ct * 2 + ks], acc[ct], 0, 0, 0);
          acc[ct] = __builtin_amdgcn_mfma_f32_16x16x32_bf16(
              xlf[ks], wfh[ct * 2 + ks], acc[ct], 0, 0, 0);
          acc[ct] = __builtin_amdgcn_mfma_f32_16x16x32_bf16(
              xhf[ks], wfl[ct * 2 + ks], acc[ct], 0, 0, 0);
        }
      }
      float fm[4];
#pragma unroll
      for (int r = 0; r < 4; ++r)
        fm[r] = reach[ech][hop][eslab + lg * 4 + r];
#pragma unroll
      for (int r = 0; r < 4; ++r) {
        if (fm[r] != 0.f) {
          const int row = eslab + lg * 4 + r;
#pragma unroll
          for (int ct = 0; ct < 4; ++ct)
            Sb[ech][row][ct * 16 + ln15] = fmaxf(acc[ct][r], 0.f);
        }
      }
    }
    __syncthreads();
  }

  // final layer 3 write
  {
#pragma unroll
    for (int u = 0; u < 2; ++u) {
      const float4 a = *(const float4*)&Sb[0][r8][cc8 + 4 * u];
      const float4 b = *(const float4*)&Sb[1][r8][cc8 + 4 * u];
      *(float4*)&out[(size_t)(nb + r8) * 256 + 192 + cc8 + 4 * u] =
          make_float4(a.x + b.x, a.y + b.y, a.z + b.z, a.w + b.w);
    }
  }
}

extern "C" void kernel_launch(void* const* d_in, const int* in_sizes, int n_in,
                              void* d_out, int out_size, void* d_ws, size_t ws_size,
                              hipStream_t stream) {
  const float* adj       = (const float*)d_in[0];
  const float* feat_node = (const float*)d_in[1];
  const int*   idx       = (const int*)d_in[2];
  const int*   head_ids  = (const int*)d_in[3];
  const int*   tail_ids  = (const int*)d_in[4];
  // d_in[5] = graph_indices (implied by block structure, unused)
  const float* transform = (const float*)d_in[6];
  const float* embed     = (const float*)d_in[7];
  const float* w1v    = (const float*)d_in[8];
  const float* b1v    = (const float*)d_in[9];
  const float* w2v    = (const float*)d_in[10];
  const float* b2v    = (const float*)d_in[11];
  const float* gamma1 = (const float*)d_in[12];
  const float* beta1  = (const float*)d_in[13];
  const float* gamma2 = (const float*)d_in[14];
  const float* beta2  = (const float*)d_in[15];

  lagat_kernel<<<64, 512, 0, stream>>>(adj, feat_node, idx, head_ids, tail_ids,
      transform, embed, w1v, b1v, w2v, b2v, gamma1, beta1, gamma2, beta2,
      (float*)d_out);
}